// Round 4
// baseline (508.878 us; speedup 1.0000x reference)
//
#include <hip/hip_runtime.h>
#include <hip/hip_bf16.h>
#include <stdint.h>

#define S 2048
#define D 64
#define BH 32
#define ROWS 64                     // rows per block
#define NT 128                      // 2 waves
#define NBLK ((BH * S) / ROWS)      // 1024 blocks -> 8/CU (LDS ~17.4KB)
#define CTX_ELEMS (BH * S * D)

typedef __attribute__((ext_vector_type(8))) __bf16 bf16x8;
typedef __attribute__((ext_vector_type(4))) float f32x4;
typedef __attribute__((ext_vector_type(4))) int   i32x4;

// Fused: per block = 64 rows of one (b,h).
// For each 512-col chunk: stream mask -> bits in LDS (pk), barrier,
// MFMA the chunk's 16 K-steps (bits @ V, V read direct from L2-resident global).
// Epilogue: ctx = acc * inv; then attn rows regenerated from LDS bits.
// No packed-bits global traffic; 1 barrier per chunk.
__global__ __launch_bounds__(NT) void k_fused(const int* __restrict__ mask,
                                              const float* __restrict__ V,
                                              float* __restrict__ ctx,
                                              float* __restrict__ attn) {
  // XCD swizzle: XCD c owns bh [4c, 4c+4) -> its V panels (2MB) stay L2-resident
  const int flat = blockIdx.x;
  const int wid = (flat & 7) * (NBLK / 8) + (flat >> 3);
  const int qt = wid & 31;          // 64-row tile within (b,h)
  const int bh = wid >> 5;

  const int t = threadIdx.x;
  const int lane = t & 63;
  const int w = t >> 6;             // wave 0..1
  const int l15 = lane & 15;
  const int lk = lane >> 4;         // 0..3

  __shared__ uint32_t pk[ROWS][65]; // full 2048 bits per row; stride 65 words
  __shared__ int pcnt[ROWS][2];
  __shared__ float invs[ROWS];

  const long R0 = (long)bh * S + (long)qt * ROWS;

  // phase-1 mapping: 2 threads per row, 256 cols each per chunk
  const int pr = t >> 1, ph = t & 1;
  const int* mrow = mask + (R0 + pr) * (long)S + ph * 256;

  const uint8_t* pkb = (const uint8_t*)pk;
  const uint8_t* aptr0 = pkb + (w * 32 + l15) * 260;       // mt=0 row bits
  const uint8_t* aptr1 = pkb + (w * 32 + 16 + l15) * 260;  // mt=1 row bits
  const float* vb = V + (long)bh * S * D + (long)lk * 8 * D + l15;

  int cnt = 0;
  f32x4 acc[2][4];
#pragma unroll
  for (int a = 0; a < 2; ++a)
#pragma unroll
    for (int b = 0; b < 4; ++b) acc[a][b] = f32x4{0.f, 0.f, 0.f, 0.f};

#pragma unroll 1
  for (int c = 0; c < 4; ++c) {
    // ---- PRODUCE chunk c: mask cols [c*512, c*512+512) -> pk words ----
    const int* mp = mrow + c * 512;
#pragma unroll
    for (int wj = 0; wj < 8; ++wj) {
      uint32_t word = 0;
#pragma unroll
      for (int b4 = 0; b4 < 4; ++b4) {
        i32x4 m0 = __builtin_nontemporal_load((const i32x4*)(mp + wj * 32 + b4 * 8));
        i32x4 m1 = __builtin_nontemporal_load((const i32x4*)(mp + wj * 32 + b4 * 8 + 4));
        uint32_t b = (m0[0] == 0 ? 1u : 0u)
                   | (m0[1] == 0 ? 2u : 0u)
                   | (m0[2] == 0 ? 4u : 0u)
                   | (m0[3] == 0 ? 8u : 0u)
                   | (m1[0] == 0 ? 16u : 0u)
                   | (m1[1] == 0 ? 32u : 0u)
                   | (m1[2] == 0 ? 64u : 0u)
                   | (m1[3] == 0 ? 128u : 0u);
        word |= b << (b4 * 8);
      }
      cnt += __popc(word);
      pk[pr][c * 16 + ph * 8 + wj] = word;
    }
    __syncthreads();   // chunk bits ready (next chunk writes different words: no 2nd barrier)

    // ---- CONSUME chunk c: 16 K-steps of MFMA ----
#pragma unroll 1
    for (int kk = c * 16; kk < c * 16 + 16; ++kk) {
      float buf[32];
      const float* vp = vb + (long)kk * 32 * D;
#pragma unroll
      for (int n4 = 0; n4 < 4; ++n4)
#pragma unroll
        for (int j = 0; j < 8; ++j)
          buf[n4 * 8 + j] = vp[j * D + n4 * 16];

      bf16x8 bf[4];
#pragma unroll
      for (int n4 = 0; n4 < 4; ++n4) {
        bf16x8 x;
#pragma unroll
        for (int j = 0; j < 8; ++j) x[j] = (__bf16)buf[n4 * 8 + j];
        bf[n4] = x;
      }
      const uint32_t by0 = aptr0[kk * 4 + lk];
      const uint32_t by1 = aptr1[kk * 4 + lk];
      union { uint32_t u[4]; bf16x8 v; } a0, a1;
#pragma unroll
      for (int p = 0; p < 4; ++p) {
        a0.u[p] = (((by0 >> (2 * p)) & 1u) ? 0x3F80u : 0u)
                | (((by0 >> (2 * p + 1)) & 1u) ? 0x3F800000u : 0u);
        a1.u[p] = (((by1 >> (2 * p)) & 1u) ? 0x3F80u : 0u)
                | (((by1 >> (2 * p + 1)) & 1u) ? 0x3F800000u : 0u);
      }
#pragma unroll
      for (int n4 = 0; n4 < 4; ++n4) {
        acc[0][n4] = __builtin_amdgcn_mfma_f32_16x16x32_bf16(a0.v, bf[n4], acc[0][n4], 0, 0, 0);
        acc[1][n4] = __builtin_amdgcn_mfma_f32_16x16x32_bf16(a1.v, bf[n4], acc[1][n4], 0, 0, 0);
      }
    }
  }

  // ---- counts -> invs ----
  pcnt[pr][ph] = cnt;
  __syncthreads();
  if (t < ROWS) {
    const int c4 = pcnt[t][0] + pcnt[t][1];
    invs[t] = (c4 > 0) ? (1.0f / (float)c4) : 0.0f;
  }
  __syncthreads();

  // ---- ctx epilogue: C/D layout col=l15, row=lk*4+ri (m89-verified) ----
#pragma unroll
  for (int mt = 0; mt < 2; ++mt) {
#pragma unroll
    for (int ri = 0; ri < 4; ++ri) {
      const int rloc = w * 32 + mt * 16 + lk * 4 + ri;
      const float iv = invs[rloc];
      const long orow = R0 + rloc;
#pragma unroll
      for (int n4 = 0; n4 < 4; ++n4)
        ctx[orow * D + n4 * 16 + l15] = acc[mt][n4][ri] * iv;
    }
  }

  // ---- attn rows from LDS bits: wave w -> rows [w*32, w*32+32) ----
#pragma unroll 1
  for (int rr = 0; rr < 32; ++rr) {
    const int r = w * 32 + rr;
    const float iv = invs[r];
    float* arow = attn + (R0 + r) * (long)S;
#pragma unroll
    for (int p = 0; p < 4; ++p) {
      const uint32_t word = pk[r][p * 16 + (lane >> 2)];   // 4 lanes/word: broadcast
      const uint32_t by = (word >> ((lane & 3) * 8)) & 0xFFu;
      f32x4 a0, a1;
      a0[0] = (by & 1u)   ? iv : 0.0f;
      a0[1] = (by & 2u)   ? iv : 0.0f;
      a0[2] = (by & 4u)   ? iv : 0.0f;
      a0[3] = (by & 8u)   ? iv : 0.0f;
      a1[0] = (by & 16u)  ? iv : 0.0f;
      a1[1] = (by & 32u)  ? iv : 0.0f;
      a1[2] = (by & 64u)  ? iv : 0.0f;
      a1[3] = (by & 128u) ? iv : 0.0f;
      __builtin_nontemporal_store(a0, (f32x4*)(arow + p * 512 + lane * 8));
      __builtin_nontemporal_store(a1, (f32x4*)(arow + p * 512 + lane * 8 + 4));
    }
  }
}

extern "C" void kernel_launch(void* const* d_in, const int* in_sizes, int n_in,
                              void* d_out, int out_size, void* d_ws, size_t ws_size,
                              hipStream_t stream) {
  (void)in_sizes; (void)n_in; (void)d_ws; (void)ws_size; (void)out_size;
  const float* V = (const float*)d_in[2];           // Q,K provably unused (mask overwrites all scores)
  const int* mask = (const int*)d_in[3];
  float* ctx = (float*)d_out;                       // output 0: [B,H,S,D]
  float* attn = (float*)d_out + (size_t)CTX_ELEMS;  // output 1: [B,H,S,S]

  k_fused<<<NBLK, NT, 0, stream>>>(mask, V, ctx, attn);
}

// Round 5
// 271.692 us; speedup vs baseline: 1.8730x; 1.8730x over previous
//
#include <hip/hip_runtime.h>
#include <hip/hip_bf16.h>
#include <stdint.h>

#define S 2048
#define D 64
#define BH 32
#define NROWS (BH * S)              // 65536
#define CTX_ELEMS (NROWS * D)
#define VT_BYTES ((size_t)BH * S * D * 2)   // 8.4 MB bf16 transposed V

typedef __attribute__((ext_vector_type(8))) __bf16 bf16x8;
typedef __attribute__((ext_vector_type(4))) float f32x4;
typedef __attribute__((ext_vector_type(4))) int   i32x4;

// ---------- Kernel 0: V[bh][k][c] f32 -> VT[bh][c][k] bf16 (d_ws) ----------
__global__ __launch_bounds__(256) void k_vt(const float* __restrict__ V,
                                            __bf16* __restrict__ VT) {
  const int bh = blockIdx.x >> 4;
  const int k0 = (blockIdx.x & 15) * 128 + (threadIdx.x >> 6) * 32;
  const int c = threadIdx.x & 63;
  const float* vp = V + ((long)bh * S + k0) * D + c;   // lane c fast -> coalesced
  __bf16* op = VT + ((long)bh * D + c) * S + k0;
#pragma unroll
  for (int j8 = 0; j8 < 4; ++j8) {
    bf16x8 o;
#pragma unroll
    for (int j = 0; j < 8; ++j) o[j] = (__bf16)vp[(long)(j8 * 8 + j) * D];
    *reinterpret_cast<bf16x8*>(op + j8 * 8) = o;
  }
}

// ---------- Kernel 1 (R1-proven): mask -> attn + packed bits ----------
__global__ __launch_bounds__(256) void k_mask(const int* __restrict__ mask,
                                              float* __restrict__ attn,
                                              uint32_t* packed) {
  const int r = blockIdx.x;
  const int t = threadIdx.x;
  const long base = (long)r * S + t * 8;

  const i32x4 m0 = __builtin_nontemporal_load((const i32x4*)(mask + base));
  const i32x4 m1 = __builtin_nontemporal_load((const i32x4*)(mask + base + 4));
  int v[8] = {m0[0], m0[1], m0[2], m0[3], m1[0], m1[1], m1[2], m1[3]};

  unsigned byte = 0;
  int cnt = 0;
#pragma unroll
  for (int j = 0; j < 8; ++j) {
    unsigned u = (v[j] == 0) ? 1u : 0u;   // 1 = unmasked
    byte |= u << j;
    cnt += (int)u;
  }
#pragma unroll
  for (int off = 32; off > 0; off >>= 1) cnt += __shfl_down(cnt, off, 64);

  __shared__ int wsum[4];
  __shared__ unsigned char bts[256];
  bts[t] = (unsigned char)byte;
  if ((t & 63) == 0) wsum[t >> 6] = cnt;
  __syncthreads();

  const int total = wsum[0] + wsum[1] + wsum[2] + wsum[3];
  const float inv = (total > 0) ? (1.0f / (float)total) : 0.0f;

  f32x4 a0, a1;
  a0[0] = (byte & 1u)   ? inv : 0.0f;
  a0[1] = (byte & 2u)   ? inv : 0.0f;
  a0[2] = (byte & 4u)   ? inv : 0.0f;
  a0[3] = (byte & 8u)   ? inv : 0.0f;
  a1[0] = (byte & 16u)  ? inv : 0.0f;
  a1[1] = (byte & 32u)  ? inv : 0.0f;
  a1[2] = (byte & 64u)  ? inv : 0.0f;
  a1[3] = (byte & 128u) ? inv : 0.0f;
  __builtin_nontemporal_store(a0, (f32x4*)(attn + base));
  __builtin_nontemporal_store(a1, (f32x4*)(attn + base + 4));

  if (t < 64) {
    uint32_t w = (uint32_t)bts[4 * t]
               | ((uint32_t)bts[4 * t + 1] << 8)
               | ((uint32_t)bts[4 * t + 2] << 16)
               | ((uint32_t)bts[4 * t + 3] << 24);
    packed[(long)r * 64 + t] = w;
  }
}

// ---------- Kernel 2: ctx = inv * (bits @ V), 64 rows/block, 1024 blocks ----------
// 2 waves; wave w owns rows [w*32, w*32+32), full N=64. B-frags: one bf16x8
// load from VT (or 8 scalar f32 + cvt in fallback). 2-deep software pipeline.
#define BMC 64
template<bool USE_VT>
__global__ __launch_bounds__(128) void k_ctx(const uint32_t* __restrict__ packed,
                                             const float* __restrict__ V,
                                             const __bf16* __restrict__ VT,
                                             float* __restrict__ ctx) {
  // XCD swizzle: each XCD owns 4 whole (b,h) -> VT panel (256KB) L2-resident
  const int flat = blockIdx.x;
  const int wid = (flat & 7) * ((NROWS / BMC) / 8) + (flat >> 3);
  const int qt = wid & 31;
  const int bh = wid >> 5;

  const int t = threadIdx.x;
  const int lane = t & 63;
  const int w = t >> 6;               // 0..1
  const int l15 = lane & 15;
  const int lk = lane >> 4;           // 0..3

  __shared__ uint32_t pk[BMC * 65];   // byte stride 260 -> bank stride 1
  __shared__ float invs[BMC];

  const long R0 = (long)bh * S + (long)qt * BMC;

  for (int i = t; i < BMC * 64; i += 128)
    pk[(i >> 6) * 65 + (i & 63)] = packed[(R0 + (i >> 6)) * 64 + (i & 63)];
  __syncthreads();

  if (t < BMC) {
    int c = 0;
#pragma unroll
    for (int i = 0; i < 64; ++i) c += __popc(pk[t * 65 + i]);
    invs[t] = (c > 0) ? (1.0f / (float)c) : 0.0f;
  }
  __syncthreads();

  const uint8_t* pkb = (const uint8_t*)pk;
  const uint8_t* aptr0 = pkb + (w * 32 + l15) * 260;
  const uint8_t* aptr1 = pkb + (w * 32 + 16 + l15) * 260;
  const __bf16* vt0 = VT + ((long)bh * D + l15) * S + lk * 8;  // +n4*16 rows, +kk*32
  const float* vf0 = V + (long)bh * S * D + (long)lk * 8 * D + l15;

  f32x4 acc[2][4];
#pragma unroll
  for (int a = 0; a < 2; ++a)
#pragma unroll
    for (int b = 0; b < 4; ++b) acc[a][b] = f32x4{0.f, 0.f, 0.f, 0.f};

  auto LOADB = [&](bf16x8* dst, int kk) {
    if (USE_VT) {
#pragma unroll
      for (int n4 = 0; n4 < 4; ++n4)
        dst[n4] = *reinterpret_cast<const bf16x8*>(vt0 + (long)n4 * 16 * S + (long)kk * 32);
    } else {
      const float* vp = vf0 + (long)kk * 32 * D;
#pragma unroll
      for (int n4 = 0; n4 < 4; ++n4) {
        bf16x8 x;
#pragma unroll
        for (int j = 0; j < 8; ++j) x[j] = (__bf16)vp[j * D + n4 * 16];
        dst[n4] = x;
      }
    }
  };

  auto COMPUTE = [&](const bf16x8* bf, uint32_t by0, uint32_t by1) {
    union { uint32_t u[4]; bf16x8 v; } a0, a1;
#pragma unroll
    for (int p = 0; p < 4; ++p) {
      a0.u[p] = (((by0 >> (2 * p)) & 1u) ? 0x3F80u : 0u)
              | (((by0 >> (2 * p + 1)) & 1u) ? 0x3F800000u : 0u);
      a1.u[p] = (((by1 >> (2 * p)) & 1u) ? 0x3F80u : 0u)
              | (((by1 >> (2 * p + 1)) & 1u) ? 0x3F800000u : 0u);
    }
#pragma unroll
    for (int n4 = 0; n4 < 4; ++n4) {
      acc[0][n4] = __builtin_amdgcn_mfma_f32_16x16x32_bf16(a0.v, bf[n4], acc[0][n4], 0, 0, 0);
      acc[1][n4] = __builtin_amdgcn_mfma_f32_16x16x32_bf16(a1.v, bf[n4], acc[1][n4], 0, 0, 0);
    }
  };

  bf16x8 bA[4], bB[4];
  uint32_t byA0, byA1, byB0, byB1;
  LOADB(bA, 0); byA0 = aptr0[lk]; byA1 = aptr1[lk];
#pragma unroll 1
  for (int kk = 0; kk < 64; kk += 2) {
    LOADB(bB, kk + 1);
    byB0 = aptr0[(kk + 1) * 4 + lk]; byB1 = aptr1[(kk + 1) * 4 + lk];
    COMPUTE(bA, byA0, byA1);
    if (kk + 2 < 64) {
      LOADB(bA, kk + 2);
      byA0 = aptr0[(kk + 2) * 4 + lk]; byA1 = aptr1[(kk + 2) * 4 + lk];
    }
    COMPUTE(bB, byB0, byB1);
  }

  // epilogue: C/D layout col=l15, row=lk*4+ri (m89-verified)
#pragma unroll
  for (int mt = 0; mt < 2; ++mt) {
#pragma unroll
    for (int ri = 0; ri < 4; ++ri) {
      const int rloc = w * 32 + mt * 16 + lk * 4 + ri;
      const float iv = invs[rloc];
      const long orow = R0 + rloc;
#pragma unroll
      for (int n4 = 0; n4 < 4; ++n4)
        ctx[orow * D + n4 * 16 + l15] = acc[mt][n4][ri] * iv;
    }
  }
}

extern "C" void kernel_launch(void* const* d_in, const int* in_sizes, int n_in,
                              void* d_out, int out_size, void* d_ws, size_t ws_size,
                              hipStream_t stream) {
  (void)in_sizes; (void)n_in; (void)out_size;
  const float* V = (const float*)d_in[2];           // Q,K provably unused (mask overwrites all scores)
  const int* mask = (const int*)d_in[3];
  float* ctx = (float*)d_out;                       // output 0: [B,H,S,D]
  float* attn = (float*)d_out + (size_t)CTX_ELEMS;  // output 1: [B,H,S,S]
  uint32_t* packed = (uint32_t*)d_out;              // scratch aliasing ctx region
  __bf16* VT = (__bf16*)d_ws;

  const bool use_vt = (ws_size >= VT_BYTES);
  if (use_vt) k_vt<<<BH * 16, 256, 0, stream>>>(V, VT);
  k_mask<<<NROWS, 256, 0, stream>>>(mask, attn, packed);
  if (use_vt)
    k_ctx<true><<<NROWS / BMC, 128, 0, stream>>>(packed, V, VT, ctx);
  else
    k_ctx<false><<<NROWS / BMC, 128, 0, stream>>>(packed, V, VT, ctx);
}